// Round 5
// baseline (1163.886 us; speedup 1.0000x reference)
//
#include <hip/hip_runtime.h>
#include <cstdint>

#define NA 20000
#define NE 80000

// per-l offsets (in floats) inside h / out buffers (atom-major, [n][i][j][c])
constexpr int HOFFc[4]   = {0, 2560000, 5120000, 10880000};
// packed rbm layout per edge: rbm0[128] rbm1[96] rbm2[64] rbm3[32]  (320 total)
constexpr int RBMOFFc[4] = {0, 128, 224, 288};
// global q (0..15) -> which l' the sh/rbm row comes from
constexpr int QLPc[16]   = {0,1,1,1,2,2,2,2,2,3,3,3,3,3,3,3};

// ---------------- Kernel 1: EquivariantRMSNorm + linear_in -> h (f32) ----------------
__global__ __launch_bounds__(256)
void k_norm_in(const float* __restrict__ f0, const float* __restrict__ f1,
               const float* __restrict__ f2, const float* __restrict__ f3,
               const float* __restrict__ gammas, const float* __restrict__ Win,
               float* __restrict__ h)
{
    const int l = blockIdx.y;
    const int S = (l < 2) ? 4 : ((l == 2) ? 9 : 16);
    const float* fsel = (l == 0) ? f0 : ((l == 1) ? f1 : ((l == 2) ? f2 : f3));
    float* hb = h + HOFFc[l];

    __shared__ float s_win[1024];
    __shared__ float s_g[32];
    __shared__ float s_fn[4][16][32];

    const int t = threadIdx.x;
    for (int i = t; i < 1024; i += 256) s_win[i] = Win[l * 1024 + i];
    if (t < 32) s_g[t] = gammas[l * 32 + t];
    __syncthreads();

    const int w = t >> 6, lane = t & 63, c = lane & 31, hlf = lane >> 5;
    const int n = blockIdx.x * 4 + w;
    const float* fp = fsel + (size_t)n * S * 32;

    float ss = 0.f;
    for (int s = hlf; s < S; s += 2) { float v = fp[s * 32 + c]; ss += v * v; }
    ss += __shfl_xor(ss, 32);
    const float scale = s_g[c] * rsqrtf(ss / (float)S + 1e-6f);

    for (int s = hlf; s < S; s += 2) s_fn[w][s][c] = fp[s * 32 + c] * scale;
    __syncthreads();

    float* hp = hb + (size_t)n * S * 32;
    for (int s = hlf; s < S; s += 2) {
        float acc = 0.f;
        #pragma unroll
        for (int ff = 0; ff < 32; ff++) acc += s_fn[w][s][ff] * s_win[ff * 32 + c];
        hp[s * 32 + c] = acc;
    }
}

// ---------------- Kernel 2: radial MLP as tiled SGEMM -> rbm (f32) + shq ----------------
__global__ __launch_bounds__(256, 2)
void k_edgeA(const float* __restrict__ rb,
             const float* __restrict__ sh0, const float* __restrict__ sh1,
             const float* __restrict__ sh2, const float* __restrict__ sh3,
             const float* __restrict__ A,
             const float* __restrict__ B0, const float* __restrict__ B1,
             const float* __restrict__ B2, const float* __restrict__ B3,
             float* __restrict__ rbm, float* __restrict__ shq)
{
    __shared__ float sm[16384];            // 64 KB total
    float* s_rb = sm;                      // [64][33] = 2112   (phase1)
    float* s_A  = sm + 2112;               // [32][128] = 4096  (phase1)
    float* s_B  = sm;                      // [128][64] = 8192  (phase2; aliases rb+A)
    float* s_hT = sm + 8192;               // [128][64] = 8192  (swizzled hid^T)

    const int t  = threadIdx.x;
    const int e0 = blockIdx.x * 64;
    const int tx = t & 15, ty = t >> 4;

    // packed sh -> shq (64 edges x 16 q)
    for (int i = t; i < 1024; i += 256) {
        const int q = i & 15, ge = e0 + (i >> 4);
        float v;
        if (q == 0)      v = sh0[ge];
        else if (q < 4)  v = sh1[ge * 3 + (q - 1)];
        else if (q < 9)  v = sh2[ge * 5 + (q - 4)];
        else             v = sh3[ge * 7 + (q - 9)];
        shq[(size_t)e0 * 16 + i] = v;
    }

    const float* Bl[4] = {B0, B1, B2, B3};
    const int    Kl[4] = {128, 96, 64, 32};

    for (int l = 0; l < 4; ++l) {
        __syncthreads();
        for (int i = t; i < 2048; i += 256)
            s_rb[(i >> 5) * 33 + (i & 31)] = rb[(size_t)l * NE * 32 + (size_t)e0 * 32 + i];
        for (int i = t; i < 4096; i += 256)
            s_A[i] = A[l * 4096 + i];
        __syncthreads();

        // phase1: hid[64][128] = silu(rb[64][32] @ A[32][128])
        float a1[4][8];
        #pragma unroll
        for (int i = 0; i < 4; ++i)
            #pragma unroll
            for (int u = 0; u < 8; ++u) a1[i][u] = 0.f;

        #pragma unroll 4
        for (int k = 0; k < 32; ++k) {
            float rr[4];
            #pragma unroll
            for (int i = 0; i < 4; ++i) rr[i] = s_rb[(ty * 4 + i) * 33 + k];
            float av[8];
            *reinterpret_cast<float4*>(&av[0]) = *reinterpret_cast<const float4*>(&s_A[k * 128 + tx * 8]);
            *reinterpret_cast<float4*>(&av[4]) = *reinterpret_cast<const float4*>(&s_A[k * 128 + tx * 8 + 4]);
            #pragma unroll
            for (int i = 0; i < 4; ++i)
                #pragma unroll
                for (int u = 0; u < 8; ++u) a1[i][u] += rr[i] * av[u];
        }
        #pragma unroll
        for (int u = 0; u < 8; ++u) {
            const int j = tx * 8 + u;
            float4 v;
            v.x = a1[0][u] / (1.f + __expf(-a1[0][u]));
            v.y = a1[1][u] / (1.f + __expf(-a1[1][u]));
            v.z = a1[2][u] / (1.f + __expf(-a1[2][u]));
            v.w = a1[3][u] / (1.f + __expf(-a1[3][u]));
            *reinterpret_cast<float4*>(&s_hT[j * 64 + ((ty ^ (j & 15)) << 2)]) = v;
        }
        __syncthreads();

        // phase2: rbm_l[64][K] = hid @ B_l
        const int K = Kl[l];
        const float* Bp = Bl[l];
        const int nt = (K + 63) >> 6;
        for (int ct = 0; ct < nt; ++ct) {
            const int c0 = ct * 64;
            for (int i = t; i < 8192; i += 256) {
                const int k = i >> 6, gc = c0 + (i & 63);
                s_B[i] = (gc < K) ? Bp[k * K + gc] : 0.f;
            }
            __syncthreads();

            float a2[4][4];
            #pragma unroll
            for (int i = 0; i < 4; ++i)
                #pragma unroll
                for (int j = 0; j < 4; ++j) a2[i][j] = 0.f;

            #pragma unroll 4
            for (int k = 0; k < 128; ++k) {
                float hv[4], bv[4];
                *reinterpret_cast<float4*>(hv) =
                    *reinterpret_cast<const float4*>(&s_hT[k * 64 + ((ty ^ (k & 15)) << 2)]);
                *reinterpret_cast<float4*>(bv) =
                    *reinterpret_cast<const float4*>(&s_B[k * 64 + (tx << 2)]);
                #pragma unroll
                for (int i = 0; i < 4; ++i)
                    #pragma unroll
                    for (int j = 0; j < 4; ++j) a2[i][j] += hv[i] * bv[j];
            }

            #pragma unroll
            for (int i = 0; i < 4; ++i) {
                const size_t eb = (size_t)(e0 + ty * 4 + i) * 320 + RBMOFFc[l] + c0 + tx * 4;
                #pragma unroll
                for (int j = 0; j < 4; ++j)
                    if (c0 + tx * 4 + j < K) rbm[eb + j] = a2[i][j];
            }
            __syncthreads();
        }
    }
}

// ---------------- CSR build ----------------
__global__ __launch_bounds__(256)
void k_hist(const int* __restrict__ centers, int* __restrict__ counts)
{
    const int e = blockIdx.x * 256 + threadIdx.x;
    if (e < NE) atomicAdd(&counts[centers[e]], 1);
}

__global__ __launch_bounds__(1024)
void k_scan(const int* __restrict__ counts, int* __restrict__ offsets)
{
    __shared__ int s_sum[1024];
    const int t = threadIdx.x;
    const int CH = 20;
    const int base = t * CH;
    int n = NA - base; n = n < 0 ? 0 : (n > CH ? CH : n);

    int tot = 0;
    for (int i = 0; i < n; i++) tot += counts[base + i];
    s_sum[t] = tot;
    __syncthreads();
    for (int off = 1; off < 1024; off <<= 1) {
        int v = (t >= off) ? s_sum[t - off] : 0;
        __syncthreads();
        s_sum[t] += v;
        __syncthreads();
    }
    int run = s_sum[t] - tot;
    for (int i = 0; i < n; i++) { offsets[base + i] = run; run += counts[base + i]; }
    if (t == 0) offsets[NA] = NE;
}

__global__ __launch_bounds__(256)
void k_fill(const int* __restrict__ centers, const int* __restrict__ offsets,
            int* __restrict__ cursor, int* __restrict__ elist)
{
    const int e = blockIdx.x * 256 + threadIdx.x;
    if (e < NE) {
        const int ctr = centers[e];
        const int pos = offsets[ctr] + atomicAdd(&cursor[ctr], 1);
        elist[pos] = e;
    }
}

// ---------------- Kernel: materialize unc2 / unc3 per edge (streaming) ----------------
// 8 edges/block (half-wave per edge). U-scales folded in. Output [e][p][c].
__global__ __launch_bounds__(256, 2)
void k_unc(const float* __restrict__ U2, const float* __restrict__ U3,
           const float* __restrict__ shq, const float* __restrict__ rbm,
           float* __restrict__ unc2, float* __restrict__ unc3)
{
    __shared__ float s_U2[81];
    __shared__ float s_U3[256];
    const int t = threadIdx.x;
    for (int i = t; i < 81; i += 256)  s_U2[i] = U2[i] * 0.57735026918962576f;
    for (int i = t; i < 256; i += 256) s_U3[i] = U3[i] * 0.5f;
    __syncthreads();

    const int w = t >> 6, lane = t & 63, c = lane & 31, half = lane >> 5;
    const int e = blockIdx.x * 8 + w * 2 + half;

    float sq[16];
    #pragma unroll
    for (int q = 0; q < 16; q++) sq[q] = shq[(size_t)e * 16 + q];

    const float* rrow = rbm + (size_t)e * 320;
    float r3[4], r2[3];
    r3[0] = rrow[0 + c];   r3[1] = rrow[128 + c];
    r3[2] = rrow[224 + c]; r3[3] = rrow[288 + c];
    r2[0] = rrow[32 + c];  r2[1] = rrow[160 + c]; r2[2] = rrow[256 + c];

    float st3[16];
    #pragma unroll
    for (int q = 0; q < 16; q++) st3[q] = sq[q] * r3[QLPc[q]];
    float st2[9];
    #pragma unroll
    for (int q = 0; q < 9; q++) st2[q] = sq[q] * r2[QLPc[q]];

    float* u3 = unc3 + (size_t)e * 16 * 32 + c;
    #pragma unroll
    for (int p = 0; p < 16; p++) {
        float a = 0.f;
        #pragma unroll
        for (int q = 0; q < 16; q++) a += s_U3[p * 16 + q] * st3[q];
        u3[p * 32] = a;
    }
    float* u2 = unc2 + (size_t)e * 9 * 32 + c;
    #pragma unroll
    for (int p = 0; p < 9; p++) {
        float a = 0.f;
        #pragma unroll
        for (int q = 0; q < 9; q++) a += s_U2[p * 9 + q] * st2[q];
        u2[p * 32] = a;
    }
}

// ---------------- pool (TP-only, reads materialized unc) ----------------
template<int P1>
__device__ __forceinline__ void pool_tp_body(
    const float* __restrict__ WoutL, const float* __restrict__ msp,
    const float* __restrict__ uncL, const float* __restrict__ hL,
    const float* __restrict__ fL, float* __restrict__ outL,
    const int* __restrict__ offsets, const int* __restrict__ elist,
    const int* __restrict__ neighbors)
{
    constexpr int S = P1 * P1;
    __shared__ float s_w[1024];
    __shared__ float s_acc[4][S * 32];

    const int t = threadIdx.x;
    for (int i = t; i < 1024; i += 256) s_w[i] = WoutL[i];
    __syncthreads();

    const int w = t >> 6, lane = t & 63, c = lane & 31, half = lane >> 5;
    const int n = blockIdx.x * 4 + w;
    const float ms = *msp;
    const int beg = offsets[n], end = offsets[n + 1];

    float acc[S];
    #pragma unroll
    for (int s = 0; s < S; s++) acc[s] = 0.f;

    const int nit = (end - beg + 1) >> 1;
    for (int it = 0; it < nit; ++it) {
        const int slot = beg + it * 2 + half;
        const bool valid = slot < end;
        const int e   = elist[valid ? slot : beg];
        const int nbr = neighbors[e];
        const float fac = valid ? 1.f : 0.f;

        float un[S], hn[S];
        const float* up = uncL + (size_t)e * (S * 32) + c;
        #pragma unroll
        for (int p = 0; p < S; p++) un[p] = fac * up[p * 32];
        const float* hp = hL + (size_t)nbr * (S * 32) + c;
        #pragma unroll
        for (int p = 0; p < S; p++) hn[p] = hp[p * 32];

        #pragma unroll
        for (int i = 0; i < P1; i++) {
            #pragma unroll
            for (int k = 0; k < P1; k++) {
                float m = 0.f;
                #pragma unroll
                for (int j = 0; j < P1; j++) m += un[i * P1 + j] * hn[j * P1 + k];
                acc[i * P1 + k] += m;
            }
        }
    }

    #pragma unroll
    for (int s = 0; s < S; s++) acc[s] += __shfl_xor(acc[s], 32);
    #pragma unroll
    for (int s = 0; s < S; s++) if ((s & 1) == half) s_acc[w][s * 32 + c] = acc[s];
    __syncthreads();

    const float* fp = fL + (size_t)n * (S * 32);
    float* op = outL + (size_t)n * (S * 32);
    for (int s = half; s < S; s += 2) {
        float o = 0.f;
        #pragma unroll
        for (int f = 0; f < 32; f++) o += s_acc[w][s * 32 + f] * s_w[f * 32 + c];
        op[s * 32 + c] = fp[s * 32 + c] + ms * o;
    }
}

__global__ __launch_bounds__(256, 2)
void k_pool_l2t(const float* __restrict__ Wout, const float* __restrict__ msp,
                const float* __restrict__ unc2, const float* __restrict__ h,
                const float* __restrict__ f2, float* __restrict__ out,
                const int* __restrict__ offsets, const int* __restrict__ elist,
                const int* __restrict__ neighbors)
{
    pool_tp_body<3>(Wout + 2048, msp, unc2, h + HOFFc[2], f2, out + HOFFc[2],
                    offsets, elist, neighbors);
}

__global__ __launch_bounds__(256, 2)
void k_pool_l3t(const float* __restrict__ Wout, const float* __restrict__ msp,
                const float* __restrict__ unc3, const float* __restrict__ h,
                const float* __restrict__ f3, float* __restrict__ out,
                const int* __restrict__ offsets, const int* __restrict__ elist,
                const int* __restrict__ neighbors)
{
    pool_tp_body<4>(Wout + 3072, msp, unc3, h + HOFFc[3], f3, out + HOFFc[3],
                    offsets, elist, neighbors);
}

// ---------------- pool (full: in-kernel uncouple; l0/l1 always, l2/l3 fallback) ----------------
template<int L, int LOWER, int P1, int VQ>
__device__ __forceinline__ void pool_full_body(
    const float* __restrict__ Up, float uscale,
    const float* __restrict__ WoutL, const float* __restrict__ msp,
    const float* __restrict__ shq, const float* __restrict__ rbm,
    const float* __restrict__ hL, const float* __restrict__ fL,
    float* __restrict__ outL,
    const int* __restrict__ offsets, const int* __restrict__ elist,
    const int* __restrict__ neighbors)
{
    constexpr int S = P1 * P1;
    __shared__ float s_U[S * S];
    __shared__ float s_w[1024];
    __shared__ float s_acc[4][S * 32];

    const int t = threadIdx.x;
    for (int i = t; i < S * S; i += 256) s_U[i] = Up[i] * uscale;
    for (int i = t; i < 1024; i += 256) s_w[i] = WoutL[i];
    __syncthreads();

    const int w = t >> 6, lane = t & 63, c = lane & 31, half = lane >> 5;
    const int n = blockIdx.x * 4 + w;
    const float ms = *msp;
    const int beg = offsets[n], end = offsets[n + 1];

    float acc[S];
    #pragma unroll
    for (int s = 0; s < S; s++) acc[s] = 0.f;

    const int nit = (end - beg + 1) >> 1;
    for (int it = 0; it < nit; ++it) {
        const int slot = beg + it * 2 + half;
        const bool valid = slot < end;
        const int e   = elist[valid ? slot : beg];
        const int nbr = neighbors[e];
        const float fac = valid ? 1.f : 0.f;

        float rv[L + 1];
        #pragma unroll
        for (int lp = 0; lp <= L; lp++)
            rv[lp] = fac * rbm[(size_t)e * 320 + RBMOFFc[lp] + LOWER + c];

        float st[VQ];
        #pragma unroll
        for (int q = 0; q < VQ; q++)
            st[q] = shq[(size_t)e * 16 + q] * rv[QLPc[q]];

        float hn[S];
        const float* hp = hL + (size_t)nbr * (S * 32) + c;
        #pragma unroll
        for (int p = 0; p < S; p++) hn[p] = hp[p * 32];

        #pragma unroll
        for (int i = 0; i < P1; i++) {
            float ur[P1];
            #pragma unroll
            for (int j = 0; j < P1; j++) {
                float a = 0.f;
                #pragma unroll
                for (int q = 0; q < VQ; q++) a += s_U[(i * P1 + j) * S + q] * st[q];
                ur[j] = a;
            }
            #pragma unroll
            for (int k = 0; k < P1; k++) {
                float m = 0.f;
                #pragma unroll
                for (int j = 0; j < P1; j++) m += ur[j] * hn[j * P1 + k];
                acc[i * P1 + k] += m;
            }
        }
    }

    #pragma unroll
    for (int s = 0; s < S; s++) acc[s] += __shfl_xor(acc[s], 32);
    #pragma unroll
    for (int s = 0; s < S; s++) if ((s & 1) == half) s_acc[w][s * 32 + c] = acc[s];
    __syncthreads();

    const float* fp = fL + (size_t)n * (S * 32);
    float* op = outL + (size_t)n * (S * 32);
    for (int s = half; s < S; s += 2) {
        float o = 0.f;
        #pragma unroll
        for (int f = 0; f < 32; f++) o += s_acc[w][s * 32 + f] * s_w[f * 32 + c];
        op[s * 32 + c] = fp[s * 32 + c] + ms * o;
    }
}

__global__ __launch_bounds__(256, 2)
void k_pool_l0(const float* __restrict__ U1, const float* __restrict__ Wout,
               const float* __restrict__ msp, const float* __restrict__ shq,
               const float* __restrict__ rbm, const float* __restrict__ h,
               const float* __restrict__ f0, float* __restrict__ out,
               const int* __restrict__ offsets, const int* __restrict__ elist,
               const int* __restrict__ neighbors)
{
    pool_full_body<0, 96, 2, 1>(U1, 0.70710678118654752f, Wout, msp, shq, rbm,
                                h + HOFFc[0], f0, out + HOFFc[0], offsets, elist, neighbors);
}

__global__ __launch_bounds__(256, 2)
void k_pool_l1(const float* __restrict__ U1, const float* __restrict__ Wout,
               const float* __restrict__ msp, const float* __restrict__ shq,
               const float* __restrict__ rbm, const float* __restrict__ h,
               const float* __restrict__ f1, float* __restrict__ out,
               const int* __restrict__ offsets, const int* __restrict__ elist,
               const int* __restrict__ neighbors)
{
    pool_full_body<1, 64, 2, 4>(U1, 0.70710678118654752f, Wout + 1024, msp, shq, rbm,
                                h + HOFFc[1], f1, out + HOFFc[1], offsets, elist, neighbors);
}

__global__ __launch_bounds__(256, 2)
void k_pool_l2f(const float* __restrict__ U2, const float* __restrict__ Wout,
                const float* __restrict__ msp, const float* __restrict__ shq,
                const float* __restrict__ rbm, const float* __restrict__ h,
                const float* __restrict__ f2, float* __restrict__ out,
                const int* __restrict__ offsets, const int* __restrict__ elist,
                const int* __restrict__ neighbors)
{
    pool_full_body<2, 32, 3, 9>(U2, 0.57735026918962576f, Wout + 2048, msp, shq, rbm,
                                h + HOFFc[2], f2, out + HOFFc[2], offsets, elist, neighbors);
}

__global__ __launch_bounds__(256, 2)
void k_pool_l3f(const float* __restrict__ U3, const float* __restrict__ Wout,
                const float* __restrict__ msp, const float* __restrict__ shq,
                const float* __restrict__ rbm, const float* __restrict__ h,
                const float* __restrict__ f3, float* __restrict__ out,
                const int* __restrict__ offsets, const int* __restrict__ elist,
                const int* __restrict__ neighbors)
{
    pool_full_body<3, 0, 4, 16>(U3, 0.5f, Wout + 3072, msp, shq, rbm,
                                h + HOFFc[3], f3, out + HOFFc[3], offsets, elist, neighbors);
}

// =====================================================================
extern "C" void kernel_launch(void* const* d_in, const int* in_sizes, int n_in,
                              void* d_out, int out_size, void* d_ws, size_t ws_size,
                              hipStream_t stream)
{
    (void)in_sizes; (void)n_in; (void)out_size;

    const float* rb     = (const float*)d_in[0];
    const float* sh0    = (const float*)d_in[1];
    const float* sh1    = (const float*)d_in[2];
    const float* sh2    = (const float*)d_in[3];
    const float* sh3    = (const float*)d_in[4];
    const float* f0     = (const float*)d_in[5];
    const float* f1     = (const float*)d_in[6];
    const float* f2     = (const float*)d_in[7];
    const float* f3     = (const float*)d_in[8];
    const float* U1     = (const float*)d_in[9];
    const float* U2     = (const float*)d_in[10];
    const float* U3     = (const float*)d_in[11];
    const float* gammas = (const float*)d_in[12];
    const float* Win    = (const float*)d_in[13];
    const float* Wout   = (const float*)d_in[14];
    const float* A      = (const float*)d_in[15];
    const float* B0     = (const float*)d_in[16];
    const float* B1     = (const float*)d_in[17];
    const float* B2     = (const float*)d_in[18];
    const float* B3     = (const float*)d_in[19];
    const float* msp    = (const float*)d_in[20];
    const int* centers   = (const int*)d_in[21];
    const int* neighbors = (const int*)d_in[22];

    // Layout A (primary, floats): h[21.12M] rbm[25.6M] shq[1.28M] unc2[23.04M] unc3[40.96M] + ints
    const size_t F_RBM   = 21120000;
    const size_t F_SHQ   = 46720000;
    const size_t F_UNC2  = 48000000;
    const size_t F_UNC3  = 71040000;
    const size_t F_INT_A = 112000000;
    const size_t needed_A = F_INT_A * 4 + (size_t)140001 * 4;

    // Layout B (fallback): h[21.12M] rbm[25.6M] shq[1.28M] + ints
    const size_t F_INT_B = 48000000;
    const size_t needed_B = F_INT_B * 4 + (size_t)140001 * 4;

    if (ws_size < needed_B) return;
    const bool useA = (ws_size >= needed_A);

    float* h   = (float*)d_ws;
    float* rbm = h + F_RBM;
    float* shq = h + F_SHQ;
    float* unc2 = h + F_UNC2;   // only valid under layout A
    float* unc3 = h + F_UNC3;
    int* ibase   = (int*)(h + (useA ? F_INT_A : F_INT_B));
    int* offsets = ibase;            // 20001
    int* counts  = ibase + 20001;    // 20000
    int* cursor  = ibase + 40001;    // 20000
    int* elist   = ibase + 60001;    // 80000

    hipMemsetAsync(counts, 0, (size_t)40000 * sizeof(int), stream);  // counts + cursor

    k_hist<<<313, 256, 0, stream>>>(centers, counts);
    k_scan<<<1, 1024, 0, stream>>>(counts, offsets);
    k_fill<<<313, 256, 0, stream>>>(centers, offsets, cursor, elist);

    dim3 gA(5000, 4);
    k_norm_in<<<gA, 256, 0, stream>>>(f0, f1, f2, f3, gammas, Win, h);
    k_edgeA<<<1250, 256, 0, stream>>>(rb, sh0, sh1, sh2, sh3, A, B0, B1, B2, B3, rbm, shq);

    float* out = (float*)d_out;
    k_pool_l0<<<5000, 256, 0, stream>>>(U1, Wout, msp, shq, rbm, h, f0, out, offsets, elist, neighbors);
    k_pool_l1<<<5000, 256, 0, stream>>>(U1, Wout, msp, shq, rbm, h, f1, out, offsets, elist, neighbors);

    if (useA) {
        k_unc<<<10000, 256, 0, stream>>>(U2, U3, shq, rbm, unc2, unc3);
        k_pool_l2t<<<5000, 256, 0, stream>>>(Wout, msp, unc2, h, f2, out, offsets, elist, neighbors);
        k_pool_l3t<<<5000, 256, 0, stream>>>(Wout, msp, unc3, h, f3, out, offsets, elist, neighbors);
    } else {
        k_pool_l2f<<<5000, 256, 0, stream>>>(U2, Wout, msp, shq, rbm, h, f2, out, offsets, elist, neighbors);
        k_pool_l3f<<<5000, 256, 0, stream>>>(U3, Wout, msp, shq, rbm, h, f3, out, offsets, elist, neighbors);
    }
}

// Round 6
// 756.636 us; speedup vs baseline: 1.5382x; 1.5382x over previous
//
#include <hip/hip_runtime.h>
#include <cstdint>

#define NA 20000
#define NE 80000

// per-l offsets (in floats) inside h / out buffers (atom-major, [n][i][j][c])
constexpr int HOFFc[4]   = {0, 2560000, 5120000, 10880000};
// packed rbm layout per edge: rbm0[128] rbm1[96] rbm2[64] rbm3[32]  (320 total)
constexpr int RBMOFFc[4] = {0, 128, 224, 288};
// global q (0..15) -> which l' the sh/rbm row comes from
constexpr int QLPc[16]   = {0,1,1,1,2,2,2,2,2,3,3,3,3,3,3,3};

// ---------------- Kernel 1: EquivariantRMSNorm + linear_in -> h (f32) ----------------
__global__ __launch_bounds__(256)
void k_norm_in(const float* __restrict__ f0, const float* __restrict__ f1,
               const float* __restrict__ f2, const float* __restrict__ f3,
               const float* __restrict__ gammas, const float* __restrict__ Win,
               float* __restrict__ h)
{
    const int l = blockIdx.y;
    const int S = (l < 2) ? 4 : ((l == 2) ? 9 : 16);
    const float* fsel = (l == 0) ? f0 : ((l == 1) ? f1 : ((l == 2) ? f2 : f3));
    float* hb = h + HOFFc[l];

    __shared__ float s_win[1024];
    __shared__ float s_g[32];
    __shared__ float s_fn[4][16][32];

    const int t = threadIdx.x;
    for (int i = t; i < 1024; i += 256) s_win[i] = Win[l * 1024 + i];
    if (t < 32) s_g[t] = gammas[l * 32 + t];
    __syncthreads();

    const int w = t >> 6, lane = t & 63, c = lane & 31, hlf = lane >> 5;
    const int n = blockIdx.x * 4 + w;
    const float* fp = fsel + (size_t)n * S * 32;

    float ss = 0.f;
    for (int s = hlf; s < S; s += 2) { float v = fp[s * 32 + c]; ss += v * v; }
    ss += __shfl_xor(ss, 32);
    const float scale = s_g[c] * rsqrtf(ss / (float)S + 1e-6f);

    for (int s = hlf; s < S; s += 2) s_fn[w][s][c] = fp[s * 32 + c] * scale;
    __syncthreads();

    float* hp = hb + (size_t)n * S * 32;
    for (int s = hlf; s < S; s += 2) {
        float acc = 0.f;
        #pragma unroll
        for (int ff = 0; ff < 32; ff++) acc += s_fn[w][s][ff] * s_win[ff * 32 + c];
        hp[s * 32 + c] = acc;
    }
}

// ---------------- Kernel 2: radial MLP as tiled SGEMM -> rbm (f32) + shq ----------------
__global__ __launch_bounds__(256, 2)
void k_edgeA(const float* __restrict__ rb,
             const float* __restrict__ sh0, const float* __restrict__ sh1,
             const float* __restrict__ sh2, const float* __restrict__ sh3,
             const float* __restrict__ A,
             const float* __restrict__ B0, const float* __restrict__ B1,
             const float* __restrict__ B2, const float* __restrict__ B3,
             float* __restrict__ rbm, float* __restrict__ shq)
{
    __shared__ float sm[16384];            // 64 KB total
    float* s_rb = sm;                      // [64][33] = 2112   (phase1)
    float* s_A  = sm + 2112;               // [32][128] = 4096  (phase1)
    float* s_B  = sm;                      // [128][64] = 8192  (phase2; aliases rb+A)
    float* s_hT = sm + 8192;               // [128][64] = 8192  (swizzled hid^T)

    const int t  = threadIdx.x;
    const int e0 = blockIdx.x * 64;
    const int tx = t & 15, ty = t >> 4;

    // packed sh -> shq (64 edges x 16 q)
    for (int i = t; i < 1024; i += 256) {
        const int q = i & 15, ge = e0 + (i >> 4);
        float v;
        if (q == 0)      v = sh0[ge];
        else if (q < 4)  v = sh1[ge * 3 + (q - 1)];
        else if (q < 9)  v = sh2[ge * 5 + (q - 4)];
        else             v = sh3[ge * 7 + (q - 9)];
        shq[(size_t)e0 * 16 + i] = v;
    }

    const float* Bl[4] = {B0, B1, B2, B3};
    const int    Kl[4] = {128, 96, 64, 32};

    for (int l = 0; l < 4; ++l) {
        __syncthreads();
        for (int i = t; i < 2048; i += 256)
            s_rb[(i >> 5) * 33 + (i & 31)] = rb[(size_t)l * NE * 32 + (size_t)e0 * 32 + i];
        for (int i = t; i < 4096; i += 256)
            s_A[i] = A[l * 4096 + i];
        __syncthreads();

        // phase1: hid[64][128] = silu(rb[64][32] @ A[32][128])
        float a1[4][8];
        #pragma unroll
        for (int i = 0; i < 4; ++i)
            #pragma unroll
            for (int u = 0; u < 8; ++u) a1[i][u] = 0.f;

        #pragma unroll 4
        for (int k = 0; k < 32; ++k) {
            float rr[4];
            #pragma unroll
            for (int i = 0; i < 4; ++i) rr[i] = s_rb[(ty * 4 + i) * 33 + k];
            float av[8];
            *reinterpret_cast<float4*>(&av[0]) = *reinterpret_cast<const float4*>(&s_A[k * 128 + tx * 8]);
            *reinterpret_cast<float4*>(&av[4]) = *reinterpret_cast<const float4*>(&s_A[k * 128 + tx * 8 + 4]);
            #pragma unroll
            for (int i = 0; i < 4; ++i)
                #pragma unroll
                for (int u = 0; u < 8; ++u) a1[i][u] += rr[i] * av[u];
        }
        #pragma unroll
        for (int u = 0; u < 8; ++u) {
            const int j = tx * 8 + u;
            float4 v;
            v.x = a1[0][u] / (1.f + __expf(-a1[0][u]));
            v.y = a1[1][u] / (1.f + __expf(-a1[1][u]));
            v.z = a1[2][u] / (1.f + __expf(-a1[2][u]));
            v.w = a1[3][u] / (1.f + __expf(-a1[3][u]));
            *reinterpret_cast<float4*>(&s_hT[j * 64 + ((ty ^ (j & 15)) << 2)]) = v;
        }
        __syncthreads();

        // phase2: rbm_l[64][K] = hid @ B_l
        const int K = Kl[l];
        const float* Bp = Bl[l];
        const int nt = (K + 63) >> 6;
        for (int ct = 0; ct < nt; ++ct) {
            const int c0 = ct * 64;
            for (int i = t; i < 8192; i += 256) {
                const int k = i >> 6, gc = c0 + (i & 63);
                s_B[i] = (gc < K) ? Bp[k * K + gc] : 0.f;
            }
            __syncthreads();

            float a2[4][4];
            #pragma unroll
            for (int i = 0; i < 4; ++i)
                #pragma unroll
                for (int j = 0; j < 4; ++j) a2[i][j] = 0.f;

            #pragma unroll 4
            for (int k = 0; k < 128; ++k) {
                float hv[4], bv[4];
                *reinterpret_cast<float4*>(hv) =
                    *reinterpret_cast<const float4*>(&s_hT[k * 64 + ((ty ^ (k & 15)) << 2)]);
                *reinterpret_cast<float4*>(bv) =
                    *reinterpret_cast<const float4*>(&s_B[k * 64 + (tx << 2)]);
                #pragma unroll
                for (int i = 0; i < 4; ++i)
                    #pragma unroll
                    for (int j = 0; j < 4; ++j) a2[i][j] += hv[i] * bv[j];
            }

            #pragma unroll
            for (int i = 0; i < 4; ++i) {
                const size_t eb = (size_t)(e0 + ty * 4 + i) * 320 + RBMOFFc[l] + c0 + tx * 4;
                #pragma unroll
                for (int j = 0; j < 4; ++j)
                    if (c0 + tx * 4 + j < K) rbm[eb + j] = a2[i][j];
            }
            __syncthreads();
        }
    }
}

// ---------------- CSR build ----------------
__global__ __launch_bounds__(256)
void k_hist(const int* __restrict__ centers, int* __restrict__ counts)
{
    const int e = blockIdx.x * 256 + threadIdx.x;
    if (e < NE) atomicAdd(&counts[centers[e]], 1);
}

__global__ __launch_bounds__(1024)
void k_scan(const int* __restrict__ counts, int* __restrict__ offsets)
{
    __shared__ int s_sum[1024];
    const int t = threadIdx.x;
    const int CH = 20;
    const int base = t * CH;
    int n = NA - base; n = n < 0 ? 0 : (n > CH ? CH : n);

    int tot = 0;
    for (int i = 0; i < n; i++) tot += counts[base + i];
    s_sum[t] = tot;
    __syncthreads();
    for (int off = 1; off < 1024; off <<= 1) {
        int v = (t >= off) ? s_sum[t - off] : 0;
        __syncthreads();
        s_sum[t] += v;
        __syncthreads();
    }
    int run = s_sum[t] - tot;
    for (int i = 0; i < n; i++) { offsets[base + i] = run; run += counts[base + i]; }
    if (t == 0) offsets[NA] = NE;
}

__global__ __launch_bounds__(256)
void k_fill(const int* __restrict__ centers, const int* __restrict__ offsets,
            int* __restrict__ cursor, int* __restrict__ elist)
{
    const int e = blockIdx.x * 256 + threadIdx.x;
    if (e < NE) {
        const int ctr = centers[e];
        const int pos = offsets[ctr] + atomicAdd(&cursor[ctr], 1);
        elist[pos] = e;
    }
}

// ---------------- TP step for the big-l pools (all indices compile-time) ----------------
// acc[x] accumulates output spatial slot s = ASTART + x for this lane's channel c.
template<int P1, int ASTART, int ACNT>
__device__ __forceinline__ void tp_step(float* __restrict__ acc,
                                        const float* __restrict__ lg,
                                        const float* __restrict__ lh,
                                        const float* __restrict__ rv, int c)
{
    float un[ACNT];
    #pragma unroll
    for (int pi = 0; pi < ACNT; ++pi) {
        const int p = ASTART + pi;
        float a = 0.f;
        #pragma unroll
        for (int lp = 0; lp < P1; ++lp) a += lg[p * 4 + lp] * rv[lp];
        un[pi] = a;
    }
    constexpr int ILO = ASTART / P1, INUM = ACNT / P1;
    #pragma unroll
    for (int ii = 0; ii < INUM; ++ii) {
        #pragma unroll
        for (int k = 0; k < P1; ++k) {
            float m = 0.f;
            #pragma unroll
            for (int j = 0; j < P1; ++j) m += un[ii * P1 + j] * lh[(j * P1 + k) * 32 + c];
            acc[ii * P1 + k] += m;
        }
    }
}

// ---------------- l2/l3 pool: wave-per-atom, one edge per iteration, LDS-streamed ----------------
// unc factorization: unc[p][c] = sum_lp G[p][lp] * rv[lp][c],
//   G[p][lp] = sum_{q in lp} U[p][q]*shq[q]  (channel-independent, 64 lanes <-> 64 entries).
template<int P1, int LOWER>
__global__ __launch_bounds__(256, 4)
void k_pool_big(const float* __restrict__ Up, float uscale,
                const float* __restrict__ WoutL, const float* __restrict__ msp,
                const float* __restrict__ shq, const float* __restrict__ rbm,
                const float* __restrict__ hL, const float* __restrict__ fL,
                float* __restrict__ outL,
                const int* __restrict__ offsets, const int* __restrict__ elist,
                const int* __restrict__ neighbors)
{
    constexpr int S      = P1 * P1;
    constexpr int ACNT0  = (P1 == 4) ? 8 : 6;   // half0 owns s = 0..ACNT0-1
    constexpr int ACNT1  = (P1 == 4) ? 8 : 3;   // half1 owns s = ACNT0..S-1
    constexpr int ASTART1 = ACNT0;

    __shared__ float s_U[S * S];
    __shared__ float s_w[1024];
    __shared__ float s_h[4][S * 32];   // per-wave h-row buffer (reused as acc stage)
    __shared__ float s_g[4][64];       // per-wave G buffer

    const int t = threadIdx.x;
    for (int i = t; i < S * S; i += 256) s_U[i] = Up[i] * uscale;
    for (int i = t; i < 1024; i += 256) s_w[i] = WoutL[i];
    __syncthreads();

    const int w = t >> 6, lane = t & 63, c = lane & 31, half = lane >> 5;
    const int n = blockIdx.x * 4 + w;
    const float ms = *msp;
    const int beg = offsets[n], end = offsets[n + 1];

    // G-lane mapping: lane -> (p = lane>>2, lp = lane&3)
    const int gp = lane >> 2, glp = lane & 3;
    const int qlo = (glp == 0) ? 0 : (glp == 1) ? 1 : (glp == 2) ? 4 : 9;
    const int qhi = (glp == 0) ? 1 : (glp == 1) ? 4 : (glp == 2) ? 9 : 16;
    const bool gvalid = (gp < S) && (glp < P1);

    float acc[ACNT0];
    #pragma unroll
    for (int x = 0; x < ACNT0; ++x) acc[x] = 0.f;

    float* lh = s_h[w];
    float* lg = s_g[w];

    for (int slot = beg; slot < end; ++slot) {
        const int e   = elist[slot];
        const int nbr = neighbors[e];

        // cooperative h-row load (S*32 floats, contiguous)
        const float4* hp4 = reinterpret_cast<const float4*>(hL + (size_t)nbr * (S * 32));
        float4 v0 = hp4[lane];
        float4 v1 = {};
        if constexpr (P1 == 4) { v1 = hp4[64 + lane]; }
        else                   { if (lane < 8) v1 = hp4[64 + lane]; }

        // per-channel rbm values for this group
        const float* rrow = rbm + (size_t)e * 320 + LOWER + c;
        float rv[P1];
        #pragma unroll
        for (int lp = 0; lp < P1; ++lp) rv[lp] = rrow[RBMOFFc[lp]];

        // G entry for this lane
        const float* sqp = shq + (size_t)e * 16;
        float g = 0.f;
        if (gvalid) {
            for (int q = qlo; q < qhi; ++q) g += s_U[gp * S + q] * sqp[q];
        }

        // stage to per-wave LDS (wave-synchronous; no block barrier)
        *reinterpret_cast<float4*>(&lh[lane * 4]) = v0;
        if constexpr (P1 == 4) { *reinterpret_cast<float4*>(&lh[(64 + lane) * 4]) = v1; }
        else                   { if (lane < 8) *reinterpret_cast<float4*>(&lh[(64 + lane) * 4]) = v1; }
        lg[lane] = g;

        asm volatile("s_waitcnt lgkmcnt(0)" ::: "memory");

        if (half == 0) tp_step<P1, 0,       ACNT0>(acc, lg, lh, rv, c);
        else           tp_step<P1, ASTART1, ACNT1>(acc, lg, lh, rv, c);
    }

    // stage acc into the wave's LDS buffer (halves own disjoint s)
    if (half == 0) {
        #pragma unroll
        for (int x = 0; x < ACNT0; ++x) lh[x * 32 + c] = acc[x];
    } else {
        #pragma unroll
        for (int x = 0; x < ACNT1; ++x) lh[(ASTART1 + x) * 32 + c] = acc[x];
    }
    asm volatile("s_waitcnt lgkmcnt(0)" ::: "memory");

    // Wout linear + residual
    const float* fp = fL + (size_t)n * (S * 32);
    float* op = outL + (size_t)n * (S * 32);
    for (int s = half; s < S; s += 2) {
        float o = 0.f;
        #pragma unroll
        for (int f = 0; f < 32; f++) o += lh[s * 32 + f] * s_w[f * 32 + c];
        op[s * 32 + c] = fp[s * 32 + c] + ms * o;
    }
}

// ---------------- l0/l1 pools (small S; in-kernel uncouple, unchanged) ----------------
template<int L, int LOWER, int P1, int VQ>
__device__ __forceinline__ void pool_full_body(
    const float* __restrict__ Up, float uscale,
    const float* __restrict__ WoutL, const float* __restrict__ msp,
    const float* __restrict__ shq, const float* __restrict__ rbm,
    const float* __restrict__ hL, const float* __restrict__ fL,
    float* __restrict__ outL,
    const int* __restrict__ offsets, const int* __restrict__ elist,
    const int* __restrict__ neighbors)
{
    constexpr int S = P1 * P1;
    __shared__ float s_U[S * S];
    __shared__ float s_w[1024];
    __shared__ float s_acc[4][S * 32];

    const int t = threadIdx.x;
    for (int i = t; i < S * S; i += 256) s_U[i] = Up[i] * uscale;
    for (int i = t; i < 1024; i += 256) s_w[i] = WoutL[i];
    __syncthreads();

    const int w = t >> 6, lane = t & 63, c = lane & 31, half = lane >> 5;
    const int n = blockIdx.x * 4 + w;
    const float ms = *msp;
    const int beg = offsets[n], end = offsets[n + 1];

    float acc[S];
    #pragma unroll
    for (int s = 0; s < S; s++) acc[s] = 0.f;

    const int nit = (end - beg + 1) >> 1;
    for (int it = 0; it < nit; ++it) {
        const int slot = beg + it * 2 + half;
        const bool valid = slot < end;
        const int e   = elist[valid ? slot : beg];
        const int nbr = neighbors[e];
        const float fac = valid ? 1.f : 0.f;

        float rv[L + 1];
        #pragma unroll
        for (int lp = 0; lp <= L; lp++)
            rv[lp] = fac * rbm[(size_t)e * 320 + RBMOFFc[lp] + LOWER + c];

        float st[VQ];
        #pragma unroll
        for (int q = 0; q < VQ; q++)
            st[q] = shq[(size_t)e * 16 + q] * rv[QLPc[q]];

        float hn[S];
        const float* hp = hL + (size_t)nbr * (S * 32) + c;
        #pragma unroll
        for (int p = 0; p < S; p++) hn[p] = hp[p * 32];

        #pragma unroll
        for (int i = 0; i < P1; i++) {
            float ur[P1];
            #pragma unroll
            for (int j = 0; j < P1; j++) {
                float a = 0.f;
                #pragma unroll
                for (int q = 0; q < VQ; q++) a += s_U[(i * P1 + j) * S + q] * st[q];
                ur[j] = a;
            }
            #pragma unroll
            for (int k = 0; k < P1; k++) {
                float m = 0.f;
                #pragma unroll
                for (int j = 0; j < P1; j++) m += ur[j] * hn[j * P1 + k];
                acc[i * P1 + k] += m;
            }
        }
    }

    #pragma unroll
    for (int s = 0; s < S; s++) acc[s] += __shfl_xor(acc[s], 32);
    #pragma unroll
    for (int s = 0; s < S; s++) if ((s & 1) == half) s_acc[w][s * 32 + c] = acc[s];
    __syncthreads();

    const float* fp = fL + (size_t)n * (S * 32);
    float* op = outL + (size_t)n * (S * 32);
    for (int s = half; s < S; s += 2) {
        float o = 0.f;
        #pragma unroll
        for (int f = 0; f < 32; f++) o += s_acc[w][s * 32 + f] * s_w[f * 32 + c];
        op[s * 32 + c] = fp[s * 32 + c] + ms * o;
    }
}

__global__ __launch_bounds__(256, 2)
void k_pool_l0(const float* __restrict__ U1, const float* __restrict__ Wout,
               const float* __restrict__ msp, const float* __restrict__ shq,
               const float* __restrict__ rbm, const float* __restrict__ h,
               const float* __restrict__ f0, float* __restrict__ out,
               const int* __restrict__ offsets, const int* __restrict__ elist,
               const int* __restrict__ neighbors)
{
    pool_full_body<0, 96, 2, 1>(U1, 0.70710678118654752f, Wout, msp, shq, rbm,
                                h + HOFFc[0], f0, out + HOFFc[0], offsets, elist, neighbors);
}

__global__ __launch_bounds__(256, 2)
void k_pool_l1(const float* __restrict__ U1, const float* __restrict__ Wout,
               const float* __restrict__ msp, const float* __restrict__ shq,
               const float* __restrict__ rbm, const float* __restrict__ h,
               const float* __restrict__ f1, float* __restrict__ out,
               const int* __restrict__ offsets, const int* __restrict__ elist,
               const int* __restrict__ neighbors)
{
    pool_full_body<1, 64, 2, 4>(U1, 0.70710678118654752f, Wout + 1024, msp, shq, rbm,
                                h + HOFFc[1], f1, out + HOFFc[1], offsets, elist, neighbors);
}

// =====================================================================
extern "C" void kernel_launch(void* const* d_in, const int* in_sizes, int n_in,
                              void* d_out, int out_size, void* d_ws, size_t ws_size,
                              hipStream_t stream)
{
    (void)in_sizes; (void)n_in; (void)out_size;

    const float* rb     = (const float*)d_in[0];
    const float* sh0    = (const float*)d_in[1];
    const float* sh1    = (const float*)d_in[2];
    const float* sh2    = (const float*)d_in[3];
    const float* sh3    = (const float*)d_in[4];
    const float* f0     = (const float*)d_in[5];
    const float* f1     = (const float*)d_in[6];
    const float* f2     = (const float*)d_in[7];
    const float* f3     = (const float*)d_in[8];
    const float* U1     = (const float*)d_in[9];
    const float* U2     = (const float*)d_in[10];
    const float* U3     = (const float*)d_in[11];
    const float* gammas = (const float*)d_in[12];
    const float* Win    = (const float*)d_in[13];
    const float* Wout   = (const float*)d_in[14];
    const float* A      = (const float*)d_in[15];
    const float* B0     = (const float*)d_in[16];
    const float* B1     = (const float*)d_in[17];
    const float* B2     = (const float*)d_in[18];
    const float* B3     = (const float*)d_in[19];
    const float* msp    = (const float*)d_in[20];
    const int* centers   = (const int*)d_in[21];
    const int* neighbors = (const int*)d_in[22];

    // ws layout (floats): h[21.12M] rbm[25.6M] shq[1.28M] + ints  (~192.6 MB, known to fit)
    const size_t F_RBM = 21120000;
    const size_t F_SHQ = 46720000;
    const size_t F_INT = 48000000;
    const size_t needed = F_INT * 4 + (size_t)140001 * 4;
    if (ws_size < needed) return;

    float* h   = (float*)d_ws;
    float* rbm = h + F_RBM;
    float* shq = h + F_SHQ;
    int* ibase   = (int*)(h + F_INT);
    int* offsets = ibase;            // 20001
    int* counts  = ibase + 20001;    // 20000
    int* cursor  = ibase + 40001;    // 20000
    int* elist   = ibase + 60001;    // 80000

    hipMemsetAsync(counts, 0, (size_t)40000 * sizeof(int), stream);  // counts + cursor

    k_hist<<<313, 256, 0, stream>>>(centers, counts);
    k_scan<<<1, 1024, 0, stream>>>(counts, offsets);
    k_fill<<<313, 256, 0, stream>>>(centers, offsets, cursor, elist);

    dim3 gA(5000, 4);
    k_norm_in<<<gA, 256, 0, stream>>>(f0, f1, f2, f3, gammas, Win, h);
    k_edgeA<<<1250, 256, 0, stream>>>(rb, sh0, sh1, sh2, sh3, A, B0, B1, B2, B3, rbm, shq);

    float* out = (float*)d_out;
    k_pool_l0<<<5000, 256, 0, stream>>>(U1, Wout, msp, shq, rbm, h, f0, out, offsets, elist, neighbors);
    k_pool_l1<<<5000, 256, 0, stream>>>(U1, Wout, msp, shq, rbm, h, f1, out, offsets, elist, neighbors);
    k_pool_big<3, 32><<<5000, 256, 0, stream>>>(U2, 0.57735026918962576f, Wout + 2048, msp,
                                                shq, rbm, h + HOFFc[2], f2, out + HOFFc[2],
                                                offsets, elist, neighbors);
    k_pool_big<4, 0><<<5000, 256, 0, stream>>>(U3, 0.5f, Wout + 3072, msp,
                                               shq, rbm, h + HOFFc[3], f3, out + HOFFc[3],
                                               offsets, elist, neighbors);
}

// Round 7
// 454.575 us; speedup vs baseline: 2.5604x; 1.6645x over previous
//
#include <hip/hip_runtime.h>
#include <cstdint>

#define NA 20000
#define NE 80000

typedef __attribute__((ext_vector_type(8))) short short8;
typedef __attribute__((ext_vector_type(4))) float f32x4;
typedef unsigned short ushort_t;

// per-l offsets (in floats) inside h / out buffers (atom-major, [n][i][j][c])
constexpr int HOFFc[4]   = {0, 2560000, 5120000, 10880000};
// packed rbm layout per edge: rbm0[128] rbm1[96] rbm2[64] rbm3[32]  (320 total)
constexpr int RBMOFFc[4] = {0, 128, 224, 288};
// global q (0..15) -> which l' the sh/rbm row comes from
constexpr int QLPc[16]   = {0,1,1,1,2,2,2,2,2,3,3,3,3,3,3,3};

__device__ __forceinline__ ushort_t f2bf(float x) {
    union { float f; unsigned u; } v; v.f = x;
    unsigned r = v.u + 0x7fffu + ((v.u >> 16) & 1u);
    return (ushort_t)(r >> 16);
}
__device__ __forceinline__ float bf2f(ushort_t u) {
    union { unsigned u; float f; } v; v.u = ((unsigned)u) << 16;
    return v.f;
}
__device__ __forceinline__ unsigned pack2(float a, float b) {
    return ((unsigned)f2bf(b) << 16) | (unsigned)f2bf(a);
}

// ---------------- Kernel 1: EquivariantRMSNorm + linear_in -> h (f32) ----------------
__global__ __launch_bounds__(256)
void k_norm_in(const float* __restrict__ f0, const float* __restrict__ f1,
               const float* __restrict__ f2, const float* __restrict__ f3,
               const float* __restrict__ gammas, const float* __restrict__ Win,
               float* __restrict__ h)
{
    const int l = blockIdx.y;
    const int S = (l < 2) ? 4 : ((l == 2) ? 9 : 16);
    const float* fsel = (l == 0) ? f0 : ((l == 1) ? f1 : ((l == 2) ? f2 : f3));
    float* hb = h + HOFFc[l];

    __shared__ float s_win[1024];
    __shared__ float s_g[32];
    __shared__ float s_fn[4][16][32];

    const int t = threadIdx.x;
    for (int i = t; i < 1024; i += 256) s_win[i] = Win[l * 1024 + i];
    if (t < 32) s_g[t] = gammas[l * 32 + t];
    __syncthreads();

    const int w = t >> 6, lane = t & 63, c = lane & 31, hlf = lane >> 5;
    const int n = blockIdx.x * 4 + w;
    const float* fp = fsel + (size_t)n * S * 32;

    float ss = 0.f;
    for (int s = hlf; s < S; s += 2) { float v = fp[s * 32 + c]; ss += v * v; }
    ss += __shfl_xor(ss, 32);
    const float scale = s_g[c] * rsqrtf(ss / (float)S + 1e-6f);

    for (int s = hlf; s < S; s += 2) s_fn[w][s][c] = fp[s * 32 + c] * scale;
    __syncthreads();

    float* hp = hb + (size_t)n * S * 32;
    for (int s = hlf; s < S; s += 2) {
        float acc = 0.f;
        #pragma unroll
        for (int ff = 0; ff < 32; ff++) acc += s_fn[w][s][ff] * s_win[ff * 32 + c];
        hp[s * 32 + c] = acc;
    }
}

// ---------------- one-time: build bf16 B^T cat [320][128] ----------------
__global__ __launch_bounds__(256)
void k_prep_w(const float* __restrict__ B0, const float* __restrict__ B1,
              const float* __restrict__ B2, const float* __restrict__ B3,
              ushort_t* __restrict__ BT)
{
    const int i = blockIdx.x * 256 + threadIdx.x;
    if (i >= 40960) return;
    const int n = i >> 7, k = i & 127;
    const float* src; int nl, N;
    if (n < 128)      { src = B0; nl = n;       N = 128; }
    else if (n < 224) { src = B1; nl = n - 128; N = 96;  }
    else if (n < 288) { src = B2; nl = n - 224; N = 64;  }
    else              { src = B3; nl = n - 288; N = 32;  }
    BT[i] = f2bf(src[k * N + nl]);
}

// ---------------- Kernel 2: radial MLP; phase1 f32 VALU, phase2 bf16 MFMA ----------------
// 64 edges/block, 4 waves. LDS: s_h bf16[64][128] swizzled (16KB) +
// region2 (32KB) = {s_rb f32[64][33], s_A f32[32][128]} aliased by s_bt bf16[<=128][128].
__global__ __launch_bounds__(256, 3)
void k_edgeA(const float* __restrict__ rb,
             const float* __restrict__ sh0, const float* __restrict__ sh1,
             const float* __restrict__ sh2, const float* __restrict__ sh3,
             const float* __restrict__ A, const ushort_t* __restrict__ BT,
             ushort_t* __restrict__ rbm, float* __restrict__ shq)
{
    __shared__ ushort_t s_h[8192];   // 16 KB  [64 rows][128 cols] bf16, chunk^=(row&7)
    __shared__ float    s_r2[8192];  // 32 KB  phase1: s_rb|s_A ; phase2: s_bt
    float*    s_rb = s_r2;                       // [64][33]
    float*    s_A  = s_r2 + 2112;                // [32][128]
    ushort_t* s_bt = reinterpret_cast<ushort_t*>(s_r2);  // [N_l][128] swizzled

    const int t  = threadIdx.x;
    const int e0 = blockIdx.x * 64;
    const int tx = t & 15, ty = t >> 4;
    const int w  = t >> 6, lane = t & 63;
    const int l15 = lane & 15, lg = lane >> 4;

    // packed sh -> shq (64 edges x 16 q)
    for (int i = t; i < 1024; i += 256) {
        const int q = i & 15, ge = e0 + (i >> 4);
        float v;
        if (q == 0)      v = sh0[ge];
        else if (q < 4)  v = sh1[ge * 3 + (q - 1)];
        else if (q < 9)  v = sh2[ge * 5 + (q - 4)];
        else             v = sh3[ge * 7 + (q - 9)];
        shq[(size_t)e0 * 16 + i] = v;
    }

    const int Kl[4] = {128, 96, 64, 32};

    for (int l = 0; l < 4; ++l) {
        __syncthreads();   // prior phase2 done with s_bt / s_h
        // ---- stage rb tile (f32) + A_l (f32) ----
        for (int i = t; i < 2048; i += 256)
            s_rb[(i >> 5) * 33 + (i & 31)] = rb[(size_t)l * NE * 32 + (size_t)e0 * 32 + i];
        for (int i = t; i < 4096; i += 256)
            s_A[i] = A[l * 4096 + i];
        __syncthreads();

        // ---- phase1 (f32 VALU): hid[64][128] = silu(rb @ A_l) -> s_h bf16 swizzled ----
        float a1[4][8];
        #pragma unroll
        for (int i = 0; i < 4; ++i)
            #pragma unroll
            for (int u = 0; u < 8; ++u) a1[i][u] = 0.f;

        #pragma unroll 4
        for (int k = 0; k < 32; ++k) {
            float rr[4];
            #pragma unroll
            for (int i = 0; i < 4; ++i) rr[i] = s_rb[(ty * 4 + i) * 33 + k];
            float av[8];
            *reinterpret_cast<float4*>(&av[0]) = *reinterpret_cast<const float4*>(&s_A[k * 128 + tx * 8]);
            *reinterpret_cast<float4*>(&av[4]) = *reinterpret_cast<const float4*>(&s_A[k * 128 + tx * 8 + 4]);
            #pragma unroll
            for (int i = 0; i < 4; ++i)
                #pragma unroll
                for (int u = 0; u < 8; ++u) a1[i][u] += rr[i] * av[u];
        }
        #pragma unroll
        for (int i = 0; i < 4; ++i) {
            const int row = ty * 4 + i;
            float s[8];
            #pragma unroll
            for (int u = 0; u < 8; ++u) { const float x = a1[i][u]; s[u] = x / (1.f + __expf(-x)); }
            uint4 d;
            d.x = pack2(s[0], s[1]); d.y = pack2(s[2], s[3]);
            d.z = pack2(s[4], s[5]); d.w = pack2(s[6], s[7]);
            *reinterpret_cast<uint4*>(&s_h[row * 128 + ((tx ^ (row & 7)) << 3)]) = d;
        }
        __syncthreads();

        // ---- stage B^T_l into s_bt (coalesced read, swizzled write) ----
        const int chunks = Kl[l] << 4;   // N_l * 16 chunks of 8 bf16
        for (int cch = t; cch < chunks; cch += 256) {
            const int n = cch >> 4, loc = cch & 15;
            const uint4 v = *reinterpret_cast<const uint4*>(&BT[(size_t)(RBMOFFc[l] + n) * 128 + loc * 8]);
            *reinterpret_cast<uint4*>(&s_bt[n * 128 + ((loc ^ (n & 7)) << 3)]) = v;
        }
        __syncthreads();

        // ---- phase2 (MFMA): D[n][e] = BT_l . hid^T ; lane stores 4 consecutive channels ----
        const int erow = 16 * w + l15;
        short8 hf0 = *reinterpret_cast<const short8*>(&s_h[erow * 128 + (((0 + lg) ^ (erow & 7)) << 3)]);
        short8 hf1 = *reinterpret_cast<const short8*>(&s_h[erow * 128 + (((4 + lg) ^ (erow & 7)) << 3)]);
        short8 hf2 = *reinterpret_cast<const short8*>(&s_h[erow * 128 + (((8 + lg) ^ (erow & 7)) << 3)]);
        short8 hf3 = *reinterpret_cast<const short8*>(&s_h[erow * 128 + (((12 + lg) ^ (erow & 7)) << 3)]);

        const int ntn = Kl[l] >> 4;
        for (int nt = 0; nt < ntn; ++nt) {
            const int n = nt * 16 + l15;
            f32x4 acc = {0.f, 0.f, 0.f, 0.f};
            #pragma unroll
            for (int ks = 0; ks < 4; ++ks) {
                const short8 af = *reinterpret_cast<const short8*>(
                    &s_bt[n * 128 + (((ks * 4 + lg) ^ (n & 7)) << 3)]);
                const short8 hfk = (ks == 0) ? hf0 : (ks == 1) ? hf1 : (ks == 2) ? hf2 : hf3;
                acc = __builtin_amdgcn_mfma_f32_16x16x32_bf16(af, hfk, acc, 0, 0, 0);
            }
            uint2 ov;
            ov.x = pack2(acc[0], acc[1]);
            ov.y = pack2(acc[2], acc[3]);
            *reinterpret_cast<uint2*>(&rbm[(size_t)(e0 + erow) * 320 + RBMOFFc[l] + nt * 16 + 4 * lg]) = ov;
        }
    }
}

// ---------------- CSR build ----------------
__global__ __launch_bounds__(256)
void k_hist(const int* __restrict__ centers, int* __restrict__ counts)
{
    const int e = blockIdx.x * 256 + threadIdx.x;
    if (e < NE) atomicAdd(&counts[centers[e]], 1);
}

__global__ __launch_bounds__(1024)
void k_scan(const int* __restrict__ counts, int* __restrict__ offsets)
{
    __shared__ int s_sum[1024];
    const int t = threadIdx.x;
    const int CH = 20;
    const int base = t * CH;
    int n = NA - base; n = n < 0 ? 0 : (n > CH ? CH : n);

    int tot = 0;
    for (int i = 0; i < n; i++) tot += counts[base + i];
    s_sum[t] = tot;
    __syncthreads();
    for (int off = 1; off < 1024; off <<= 1) {
        int v = (t >= off) ? s_sum[t - off] : 0;
        __syncthreads();
        s_sum[t] += v;
        __syncthreads();
    }
    int run = s_sum[t] - tot;
    for (int i = 0; i < n; i++) { offsets[base + i] = run; run += counts[base + i]; }
    if (t == 0) offsets[NA] = NE;
}

__global__ __launch_bounds__(256)
void k_fill(const int* __restrict__ centers, const int* __restrict__ offsets,
            int* __restrict__ cursor, int* __restrict__ elist)
{
    const int e = blockIdx.x * 256 + threadIdx.x;
    if (e < NE) {
        const int ctr = centers[e];
        const int pos = offsets[ctr] + atomicAdd(&cursor[ctr], 1);
        elist[pos] = e;
    }
}

// ---------------- TP step for the big-l pools (all indices compile-time) ----------------
template<int P1, int ASTART, int ACNT>
__device__ __forceinline__ void tp_step(float* __restrict__ acc,
                                        const float* __restrict__ lg,
                                        const float* __restrict__ lh,
                                        const float* __restrict__ rv, int c)
{
    float un[ACNT];
    #pragma unroll
    for (int pi = 0; pi < ACNT; ++pi) {
        const int p = ASTART + pi;
        float a = 0.f;
        #pragma unroll
        for (int lp = 0; lp < P1; ++lp) a += lg[p * 4 + lp] * rv[lp];
        un[pi] = a;
    }
    #pragma unroll
    for (int ii = 0; ii < ACNT / P1; ++ii) {
        #pragma unroll
        for (int k = 0; k < P1; ++k) {
            float m = 0.f;
            #pragma unroll
            for (int j = 0; j < P1; ++j) m += un[ii * P1 + j] * lh[(j * P1 + k) * 32 + c];
            acc[ii * P1 + k] += m;
        }
    }
}

// ---------------- l2/l3 pool: wave-per-atom, one edge per iteration, LDS-streamed ----------------
template<int P1, int LOWER>
__global__ __launch_bounds__(256, 4)
void k_pool_big(const float* __restrict__ Up, float uscale,
                const float* __restrict__ WoutL, const float* __restrict__ msp,
                const float* __restrict__ shq, const ushort_t* __restrict__ rbm,
                const float* __restrict__ hL, const float* __restrict__ fL,
                float* __restrict__ outL,
                const int* __restrict__ offsets, const int* __restrict__ elist,
                const int* __restrict__ neighbors)
{
    constexpr int S      = P1 * P1;
    constexpr int ACNT0  = (P1 == 4) ? 8 : 6;
    constexpr int ACNT1  = (P1 == 4) ? 8 : 3;
    constexpr int ASTART1 = ACNT0;

    __shared__ float s_U[S * S];
    __shared__ float s_w[1024];
    __shared__ float s_h[4][S * 32];
    __shared__ float s_g[4][64];

    const int t = threadIdx.x;
    for (int i = t; i < S * S; i += 256) s_U[i] = Up[i] * uscale;
    for (int i = t; i < 1024; i += 256) s_w[i] = WoutL[i];
    __syncthreads();

    const int w = t >> 6, lane = t & 63, c = lane & 31, half = lane >> 5;
    const int n = blockIdx.x * 4 + w;
    const float ms = *msp;
    const int beg = offsets[n], end = offsets[n + 1];

    const int gp = lane >> 2, glp = lane & 3;
    const int qlo = (glp == 0) ? 0 : (glp == 1) ? 1 : (glp == 2) ? 4 : 9;
    const int qhi = (glp == 0) ? 1 : (glp == 1) ? 4 : (glp == 2) ? 9 : 16;
    const bool gvalid = (gp < S) && (glp < P1);

    float acc[ACNT0];
    #pragma unroll
    for (int x = 0; x < ACNT0; ++x) acc[x] = 0.f;

    float* lh = s_h[w];
    float* lgb = s_g[w];

    for (int slot = beg; slot < end; ++slot) {
        const int e   = elist[slot];
        const int nbr = neighbors[e];

        const float4* hp4 = reinterpret_cast<const float4*>(hL + (size_t)nbr * (S * 32));
        float4 v0 = hp4[lane];
        float4 v1 = {};
        if constexpr (P1 == 4) { v1 = hp4[64 + lane]; }
        else                   { if (lane < 8) v1 = hp4[64 + lane]; }

        const ushort_t* rrow = rbm + (size_t)e * 320 + LOWER + c;
        float rv[P1];
        #pragma unroll
        for (int lp = 0; lp < P1; ++lp) rv[lp] = bf2f(rrow[RBMOFFc[lp]]);

        const float* sqp = shq + (size_t)e * 16;
        float g = 0.f;
        if (gvalid) {
            for (int q = qlo; q < qhi; ++q) g += s_U[gp * S + q] * sqp[q];
        }

        *reinterpret_cast<float4*>(&lh[lane * 4]) = v0;
        if constexpr (P1 == 4) { *reinterpret_cast<float4*>(&lh[(64 + lane) * 4]) = v1; }
        else                   { if (lane < 8) *reinterpret_cast<float4*>(&lh[(64 + lane) * 4]) = v1; }
        lgb[lane] = g;

        asm volatile("s_waitcnt lgkmcnt(0)" ::: "memory");

        if (half == 0) tp_step<P1, 0,       ACNT0>(acc, lgb, lh, rv, c);
        else           tp_step<P1, ASTART1, ACNT1>(acc, lgb, lh, rv, c);
    }

    if (half == 0) {
        #pragma unroll
        for (int x = 0; x < ACNT0; ++x) lh[x * 32 + c] = acc[x];
    } else {
        #pragma unroll
        for (int x = 0; x < ACNT1; ++x) lh[(ASTART1 + x) * 32 + c] = acc[x];
    }
    asm volatile("s_waitcnt lgkmcnt(0)" ::: "memory");

    const float* fp = fL + (size_t)n * (S * 32);
    float* op = outL + (size_t)n * (S * 32);
    for (int s = half; s < S; s += 2) {
        float o = 0.f;
        #pragma unroll
        for (int f = 0; f < 32; f++) o += lh[s * 32 + f] * s_w[f * 32 + c];
        op[s * 32 + c] = fp[s * 32 + c] + ms * o;
    }
}

// ---------------- l0/l1 pools (small S; in-kernel uncouple) ----------------
template<int L, int LOWER, int P1, int VQ>
__device__ __forceinline__ void pool_full_body(
    const float* __restrict__ Up, float uscale,
    const float* __restrict__ WoutL, const float* __restrict__ msp,
    const float* __restrict__ shq, const ushort_t* __restrict__ rbm,
    const float* __restrict__ hL, const float* __restrict__ fL,
    float* __restrict__ outL,
    const int* __restrict__ offsets, const int* __restrict__ elist,
    const int* __restrict__ neighbors)
{
    constexpr int S = P1 * P1;
    __shared__ float s_U[S * S];
    __shared__ float s_w[1024];
    __shared__ float s_acc[4][S * 32];

    const int t = threadIdx.x;
    for (int i = t; i < S * S; i += 256) s_U[i] = Up[i] * uscale;
    for (int i = t; i < 1024; i += 256) s_w[i] = WoutL[i];
    __syncthreads();

    const int w = t >> 6, lane = t & 63, c = lane & 31, half = lane >> 5;
    const int n = blockIdx.x * 4 + w;
    const float ms = *msp;
    const int beg = offsets[n], end = offsets[n + 1];

    float acc[S];
    #pragma unroll
    for (int s = 0; s < S; s++) acc[s] = 0.f;

    const int nit = (end - beg + 1) >> 1;
    for (int it = 0; it < nit; ++it) {
        const int slot = beg + it * 2 + half;
        const bool valid = slot < end;
        const int e   = elist[valid ? slot : beg];
        const int nbr = neighbors[e];
        const float fac = valid ? 1.f : 0.f;

        float rv[L + 1];
        #pragma unroll
        for (int lp = 0; lp <= L; lp++)
            rv[lp] = fac * bf2f(rbm[(size_t)e * 320 + RBMOFFc[lp] + LOWER + c]);

        float st[VQ];
        #pragma unroll
        for (int q = 0; q < VQ; q++)
            st[q] = shq[(size_t)e * 16 + q] * rv[QLPc[q]];

        float hn[S];
        const float* hp = hL + (size_t)nbr * (S * 32) + c;
        #pragma unroll
        for (int p = 0; p < S; p++) hn[p] = hp[p * 32];

        #pragma unroll
        for (int i = 0; i < P1; i++) {
            float ur[P1];
            #pragma unroll
            for (int j = 0; j < P1; j++) {
                float a = 0.f;
                #pragma unroll
                for (int q = 0; q < VQ; q++) a += s_U[(i * P1 + j) * S + q] * st[q];
                ur[j] = a;
            }
            #pragma unroll
            for (int k = 0; k < P1; k++) {
                float m = 0.f;
                #pragma unroll
                for (int j = 0; j < P1; j++) m += ur[j] * hn[j * P1 + k];
                acc[i * P1 + k] += m;
            }
        }
    }

    #pragma unroll
    for (int s = 0; s < S; s++) acc[s] += __shfl_xor(acc[s], 32);
    #pragma unroll
    for (int s = 0; s < S; s++) if ((s & 1) == half) s_acc[w][s * 32 + c] = acc[s];
    __syncthreads();

    const float* fp = fL + (size_t)n * (S * 32);
    float* op = outL + (size_t)n * (S * 32);
    for (int s = half; s < S; s += 2) {
        float o = 0.f;
        #pragma unroll
        for (int f = 0; f < 32; f++) o += s_acc[w][s * 32 + f] * s_w[f * 32 + c];
        op[s * 32 + c] = fp[s * 32 + c] + ms * o;
    }
}

__global__ __launch_bounds__(256, 2)
void k_pool_l0(const float* __restrict__ U1, const float* __restrict__ Wout,
               const float* __restrict__ msp, const float* __restrict__ shq,
               const ushort_t* __restrict__ rbm, const float* __restrict__ h,
               const float* __restrict__ f0, float* __restrict__ out,
               const int* __restrict__ offsets, const int* __restrict__ elist,
               const int* __restrict__ neighbors)
{
    pool_full_body<0, 96, 2, 1>(U1, 0.70710678118654752f, Wout, msp, shq, rbm,
                                h + HOFFc[0], f0, out + HOFFc[0], offsets, elist, neighbors);
}

__global__ __launch_bounds__(256, 2)
void k_pool_l1(const float* __restrict__ U1, const float* __restrict__ Wout,
               const float* __restrict__ msp, const float* __restrict__ shq,
               const ushort_t* __restrict__ rbm, const float* __restrict__ h,
               const float* __restrict__ f1, float* __restrict__ out,
               const int* __restrict__ offsets, const int* __restrict__ elist,
               const int* __restrict__ neighbors)
{
    pool_full_body<1, 64, 2, 4>(U1, 0.70710678118654752f, Wout + 1024, msp, shq, rbm,
                                h + HOFFc[1], f1, out + HOFFc[1], offsets, elist, neighbors);
}

// =====================================================================
extern "C" void kernel_launch(void* const* d_in, const int* in_sizes, int n_in,
                              void* d_out, int out_size, void* d_ws, size_t ws_size,
                              hipStream_t stream)
{
    (void)in_sizes; (void)n_in; (void)out_size;

    const float* rb     = (const float*)d_in[0];
    const float* sh0    = (const float*)d_in[1];
    const float* sh1    = (const float*)d_in[2];
    const float* sh2    = (const float*)d_in[3];
    const float* sh3    = (const float*)d_in[4];
    const float* f0     = (const float*)d_in[5];
    const float* f1     = (const float*)d_in[6];
    const float* f2     = (const float*)d_in[7];
    const float* f3     = (const float*)d_in[8];
    const float* U1     = (const float*)d_in[9];
    const float* U2     = (const float*)d_in[10];
    const float* U3     = (const float*)d_in[11];
    const float* gammas = (const float*)d_in[12];
    const float* Win    = (const float*)d_in[13];
    const float* Wout   = (const float*)d_in[14];
    const float* A      = (const float*)d_in[15];
    const float* B0     = (const float*)d_in[16];
    const float* B1     = (const float*)d_in[17];
    const float* B2     = (const float*)d_in[18];
    const float* B3     = (const float*)d_in[19];
    const float* msp    = (const float*)d_in[20];
    const int* centers   = (const int*)d_in[21];
    const int* neighbors = (const int*)d_in[22];

    // ws layout (bytes):
    //   h    f32   @ 0           : 84,480,000
    //   rbm  bf16  @ 84,480,000  : 51,200,000
    //   shq  f32   @ 135,680,000 :  5,120,000
    //   BT   bf16  @ 140,800,000 :     81,920
    //   ints       @ 140,881,920 :    560,004
    const size_t OFF_RBM = 84480000;
    const size_t OFF_SHQ = 135680000;
    const size_t OFF_BT  = 140800000;
    const size_t OFF_INT = 140881920;
    const size_t needed  = OFF_INT + (size_t)140001 * 4;
    if (ws_size < needed) return;

    float*    h   = (float*)d_ws;
    ushort_t* rbm = (ushort_t*)((char*)d_ws + OFF_RBM);
    float*    shq = (float*)((char*)d_ws + OFF_SHQ);
    ushort_t* BT  = (ushort_t*)((char*)d_ws + OFF_BT);
    int* ibase   = (int*)((char*)d_ws + OFF_INT);
    int* offsets = ibase;            // 20001
    int* counts  = ibase + 20001;    // 20000
    int* cursor  = ibase + 40001;    // 20000
    int* elist   = ibase + 60001;    // 80000

    hipMemsetAsync(counts, 0, (size_t)40000 * sizeof(int), stream);  // counts + cursor

    k_hist<<<313, 256, 0, stream>>>(centers, counts);
    k_scan<<<1, 1024, 0, stream>>>(counts, offsets);
    k_fill<<<313, 256, 0, stream>>>(centers, offsets, cursor, elist);
    k_prep_w<<<160, 256, 0, stream>>>(B0, B1, B2, B3, BT);

    dim3 gA(5000, 4);
    k_norm_in<<<gA, 256, 0, stream>>>(f0, f1, f2, f3, gammas, Win, h);
    k_edgeA<<<1250, 256, 0, stream>>>(rb, sh0, sh1, sh2, sh3, A, BT, rbm, shq);

    float* out = (float*)d_out;
    k_pool_l0<<<5000, 256, 0, stream>>>(U1, Wout, msp, shq, rbm, h, f0, out, offsets, elist, neighbors);
    k_pool_l1<<<5000, 256, 0, stream>>>(U1, Wout, msp, shq, rbm, h, f1, out, offsets, elist, neighbors);
    k_pool_big<3, 32><<<5000, 256, 0, stream>>>(U2, 0.57735026918962576f, Wout + 2048, msp,
                                                shq, rbm, h + HOFFc[2], f2, out + HOFFc[2],
                                                offsets, elist, neighbors);
    k_pool_big<4, 0><<<5000, 256, 0, stream>>>(U3, 0.5f, Wout + 3072, msp,
                                               shq, rbm, h + HOFFc[3], f3, out + HOFFc[3],
                                               offsets, elist, neighbors);
}